// Round 12
// baseline (170.111 us; speedup 1.0000x reference)
//
#include <hip/hip_runtime.h>
#include <hip/hip_bf16.h>
#include <hip/hip_fp16.h>
#include <math.h>

#define BB 8192
#define NF 1024
#define KKc 2016
#define DD 64

typedef unsigned short u16;
typedef __attribute__((ext_vector_type(4))) float f32x4;
typedef __attribute__((ext_vector_type(4))) unsigned int u32x4;
typedef __attribute__((ext_vector_type(8))) short s16x8;
typedef __attribute__((ext_vector_type(8))) _Float16 f16x8;
typedef __attribute__((ext_vector_type(8))) unsigned short u16x8;

union BF2U { __hip_bfloat162 b; unsigned u; };
union H2U { __half2 h; unsigned u; };
union F16U { s16x8 s; f16x8 h; };

__device__ __forceinline__ unsigned pk_hi(float a, float b, float& fa, float& fb) {
  BF2U r; r.b = __float22bfloat162_rn(make_float2(a, b));
  float2 f = __bfloat1622float2(r.b);
  fa = f.x; fb = f.y;
  return r.u;
}
__device__ __forceinline__ unsigned pk(float a, float b) {
  BF2U r; r.b = __float22bfloat162_rn(make_float2(a, b));
  return r.u;
}
__device__ __forceinline__ unsigned pkh(float a, float b) {
  H2U r; r.h = __float22half2_rn(make_float2(a, b));
  return r.u;
}

__device__ __forceinline__ void split4(const float t0, const float t1, const float t2,
                                       const float t3, uint2& h, uint2& l) {
  float f0, f1, f2, f3;
  h.x = pk_hi(t0, t1, f0, f1);
  h.y = pk_hi(t2, t3, f2, f3);
  l.x = pk(t0 - f0, t1 - f1);
  l.y = pk(t2 - f2, t3 - f3);
}

// ---------------- Fused prepass: xf = fp16(silu(x)); wfp = fp16(W) padded ----------------
__global__ __launch_bounds__(256)
void prep_f16_kernel(const float* __restrict__ x, const float* __restrict__ W,
                     u16* __restrict__ xf, u16* __restrict__ wfp) {
  const int bid = blockIdx.x;
  if (bid < BB) {                                   // x: 8192 blocks of 1024 floats
    const int idx = bid * 256 + threadIdx.x;
    float4 vv = ((const float4*)x)[idx];
    float a[4] = {vv.x, vv.y, vv.z, vv.w};
#pragma unroll
    for (int i = 0; i < 4; i++) a[i] = a[i] / (1.f + __expf(-a[i]));
    uint2 o;
    o.x = pkh(a[0], a[1]);
    o.y = pkh(a[2], a[3]);
    ((uint2*)xf)[idx] = o;
  } else {                                          // W: 2048 blocks over 2048x1024
    const int idx = (bid - BB) * 256 + threadIdx.x;
    const int row = idx >> 8;
    float4 vv = make_float4(0.f, 0.f, 0.f, 0.f);
    if (row < KKc) vv = ((const float4*)W)[idx];
    uint2 o;
    o.x = pkh(vv.x, vv.y);
    o.y = pkh(vv.z, vv.w);
    ((uint2*)wfp)[idx] = o;
  }
}

// ---------------- Kernel 1: v = silu(x)@W^T + b via 1-pass fp16 MFMA ----------------
typedef __attribute__((address_space(1))) const unsigned int gu32;
typedef __attribute__((address_space(3))) unsigned int lu32;

__device__ __forceinline__ void gload_lds16(const void* g, void* l) {
  __builtin_amdgcn_global_load_lds((gu32*)g, (lu32*)l, 16, 0, 0);
}

__device__ __forceinline__ s16x8 frag_row32(const u16* T, int row, int kc) {
  const int c = kc ^ ((row >> 1) & 3);
  return *(const s16x8*)(T + row * 32 + c * 8);
}

__global__ __launch_bounds__(256, 4)
void gemm_f16_kernel(const u16* __restrict__ xf, const u16* __restrict__ wfp,
                     const float* __restrict__ bias, float* __restrict__ v) {
  __shared__ __align__(16) u16 Af[128 * 32];
  __shared__ __align__(16) u16 Bf[128 * 32];
  const int tid = threadIdx.x;
  const int l = tid & 63, w = tid >> 6;
  const int wi = w >> 1, wj = w & 1;
  const int lin = (blockIdx.x & 7) * 128 + (blockIdx.x >> 3);
  const int n0 = (lin & 15) * 128;
  const int m0 = (lin >> 4) * 128;
  const int kc = l >> 4, lr = l & 15;

  const u16* P = (w < 2) ? xf : wfp;
  u16* T = (w < 2) ? Af : Bf;
  const int row0 = ((w < 2) ? m0 : n0) + (w & 1) * 64;
  u16* Th = T + (w & 1) * 2048;

  f32x4 acc[4][4];
  const f32x4 zz = {0.f, 0.f, 0.f, 0.f};
#pragma unroll
  for (int a = 0; a < 4; a++)
#pragma unroll
    for (int b = 0; b < 4; b++) acc[a][b] = zz;

  for (int k0 = 0; k0 < NF; k0 += 32) {
#pragma unroll
    for (int c4 = 0; c4 < 4; c4++) {
      const int slot = c4 * 64 + l;
      const int r = slot >> 2;
      const int c = (slot & 3) ^ ((r >> 1) & 3);
      gload_lds16(P + (size_t)(row0 + r) * NF + k0 + c * 8, Th + c4 * 512);
    }
    __syncthreads();

    F16U fa[4], fb[4];
#pragma unroll
    for (int a = 0; a < 4; a++) fa[a].s = frag_row32(Af, wi * 64 + a * 16 + lr, kc);
#pragma unroll
    for (int b = 0; b < 4; b++) fb[b].s = frag_row32(Bf, wj * 64 + b * 16 + lr, kc);
#pragma unroll
    for (int b = 0; b < 4; b++)
#pragma unroll
      for (int a = 0; a < 4; a++)
        acc[a][b] = __builtin_amdgcn_mfma_f32_16x16x32_f16(fa[a].h, fb[b].h, acc[a][b], 0, 0, 0);
    __syncthreads();
  }

  const int grp = l >> 4;
#pragma unroll
  for (int b = 0; b < 4; b++) {
    const int n = n0 + wj * 64 + b * 16 + lr;
    if (n < KKc) {
      const float bb = bias[n];
#pragma unroll
      for (int a = 0; a < 4; a++) {
        const int mbase = m0 + wi * 64 + a * 16 + grp * 4;
#pragma unroll
        for (int i = 0; i < 4; i++)
          v[(size_t)(mbase + i) * KKc + n] = acc[a][b][i] + bb;
      }
    }
  }
}

// ---------------- Fallback fp32 GEMM (if ws too small) ----------------
#define BM 128
#define BN 128
#define BKr 16
#define XST 132

__global__ __launch_bounds__(256, 2)
void gemm_silu_kernel(const float* __restrict__ x, const float* __restrict__ W,
                      const float* __restrict__ bias, float* __restrict__ v) {
  __shared__ float xs[BKr * XST];
  __shared__ float wl[BKr * XST];
  const int tid = threadIdx.x;
  const int tx = tid & 15, ty = tid >> 4;
  const int c0g = blockIdx.x * BN;
  const int m0 = blockIdx.y * BM;
  const int lrow = tid >> 2;
  const int lu = (tid & 3) << 2;

  float acc[2][2][4][4];
#pragma unroll
  for (int a = 0; a < 2; a++)
#pragma unroll
    for (int b = 0; b < 2; b++)
#pragma unroll
      for (int i = 0; i < 4; i++)
#pragma unroll
        for (int j = 0; j < 4; j++) acc[a][b][i][j] = 0.f;

  for (int n0 = 0; n0 < NF; n0 += BKr) {
#pragma unroll
    for (int p = 0; p < 2; p++) {
      const int row = lrow + 64 * p;
      float4 xv = *(const float4*)(x + (size_t)(m0 + row) * NF + n0 + lu);
      float xa[4] = {xv.x, xv.y, xv.z, xv.w};
#pragma unroll
      for (int u = 0; u < 4; u++) {
        const float val = xa[u];
        xs[(lu + u) * XST + row] = val / (1.f + __expf(-val));
      }
      const int wr = c0g + row;
      float4 wv = make_float4(0.f, 0.f, 0.f, 0.f);
      if (wr < KKc) wv = *(const float4*)(W + (size_t)wr * NF + n0 + lu);
      float wa[4] = {wv.x, wv.y, wv.z, wv.w};
#pragma unroll
      for (int u = 0; u < 4; u++) wl[(lu + u) * XST + row] = wa[u];
    }
    __syncthreads();
#pragma unroll
    for (int k0 = 0; k0 < BKr; k0 += 4) {
#pragma unroll
      for (int kk = 0; kk < 4; kk++) {
        const float* xr = xs + (k0 + kk) * XST;
        const float* wr_ = wl + (k0 + kk) * XST;
        float4 t;
        t = *(const float4*)(xr + 4 * ty);       float a0[4] = {t.x, t.y, t.z, t.w};
        t = *(const float4*)(xr + 64 + 4 * ty);  float a1[4] = {t.x, t.y, t.z, t.w};
        t = *(const float4*)(wr_ + 4 * tx);      float b0[4] = {t.x, t.y, t.z, t.w};
        t = *(const float4*)(wr_ + 64 + 4 * tx); float b1[4] = {t.x, t.y, t.z, t.w};
#pragma unroll
        for (int i = 0; i < 4; i++)
#pragma unroll
          for (int j = 0; j < 4; j++) {
            acc[0][0][i][j] = fmaf(a0[i], b0[j], acc[0][0][i][j]);
            acc[0][1][i][j] = fmaf(a0[i], b1[j], acc[0][1][i][j]);
            acc[1][0][i][j] = fmaf(a1[i], b0[j], acc[1][0][i][j]);
            acc[1][1][i][j] = fmaf(a1[i], b1[j], acc[1][1][i][j]);
          }
      }
    }
    __syncthreads();
  }
#pragma unroll
  for (int rb = 0; rb < 2; rb++)
#pragma unroll
    for (int ii = 0; ii < 4; ii++) {
      const int row = m0 + rb * 64 + 4 * ty + ii;
#pragma unroll
      for (int cb = 0; cb < 2; cb++) {
        const int c = c0g + cb * 64 + 4 * tx;
        if (c < KKc) {
          float4 bb = *(const float4*)(bias + c);
          float4 o;
          o.x = acc[rb][cb][ii][0] + bb.x;
          o.y = acc[rb][cb][ii][1] + bb.y;
          o.z = acc[rb][cb][ii][2] + bb.z;
          o.w = acc[rb][cb][ii][3] + bb.w;
          *(float4*)(v + (size_t)row * KKc + c) = o;
        }
      }
    }
}

// ---------------- Kernel 2: expm(skew(v_row)) ----------------
// Plane layout: u16[64][64]; 16B chunk swizzle chunk' = chunk ^ (row&7).
// mat_mm1h(P,Q) computes rows(P)·rows(Q)^T. Skew A: A·A^T = -A^2.
// Fixed exact prescales (powers of 2): X2 = 2^-4 A^2 (fp16), X4 = 2^-8 A^4.

__device__ __forceinline__ s16x8 fragld(const u16* P, int row, int chunk) {
  return *(const s16x8*)(P + ((row << 6) | ((chunk ^ (row & 7)) << 3)));
}

// split-bf16 3-pass: acc += A·B (B symmetric, row-read)
__device__ __forceinline__ void mat_mm3(const u16* APh, const u16* APl,
                                        const u16* BPh, const u16* BPl,
                                        f32x4 acc[2][2], int wi, int wj, int g, int lr) {
#pragma unroll
  for (int kb = 0; kb < 2; kb++) {
    const int ch = (kb << 2) | g;
    s16x8 bh[2], bl[2];
#pragma unroll
    for (int b = 0; b < 2; b++) {
      const int n = wj * 32 + b * 16 + lr;
      bh[b] = fragld(BPh, n, ch);
      bl[b] = fragld(BPl, n, ch);
    }
#pragma unroll
    for (int a = 0; a < 2; a++) {
      const int r = wi * 32 + a * 16 + lr;
      const s16x8 ah = fragld(APh, r, ch);
      const s16x8 al = fragld(APl, r, ch);
#pragma unroll
      for (int b = 0; b < 2; b++) {
        acc[a][b] = __builtin_amdgcn_mfma_f32_16x16x32_bf16(ah, bh[b], acc[a][b], 0, 0, 0);
        acc[a][b] = __builtin_amdgcn_mfma_f32_16x16x32_bf16(ah, bl[b], acc[a][b], 0, 0, 0);
        acc[a][b] = __builtin_amdgcn_mfma_f32_16x16x32_bf16(al, bh[b], acc[a][b], 0, 0, 0);
      }
    }
  }
}

// fp16 1-pass: acc += rows(AP)·rows(BP)^T
__device__ __forceinline__ void mat_mm1h(const u16* AP, const u16* BP,
                                         f32x4 acc[2][2], int wi, int wj, int g, int lr) {
#pragma unroll
  for (int kb = 0; kb < 2; kb++) {
    const int ch = (kb << 2) | g;
    F16U bh[2];
#pragma unroll
    for (int b = 0; b < 2; b++) bh[b].s = fragld(BP, wj * 32 + b * 16 + lr, ch);
#pragma unroll
    for (int a = 0; a < 2; a++) {
      F16U ah; ah.s = fragld(AP, wi * 32 + a * 16 + lr, ch);
#pragma unroll
      for (int b = 0; b < 2; b++)
        acc[a][b] = __builtin_amdgcn_mfma_f32_16x16x32_f16(ah.h, bh[b].h, acc[a][b], 0, 0, 0);
    }
  }
}

// col-copy write, split bf16 (symmetric => col-copy == row-major)
__device__ __forceinline__ void pack_col(u16* Ch, u16* Cl, const f32x4 acc[2][2],
                                         int wi, int wj, int g, int lr) {
#pragma unroll
  for (int a = 0; a < 2; a++) {
    const int r0 = wi * 32 + a * 16 + g * 4;
#pragma unroll
    for (int b = 0; b < 2; b++) {
      const int c = wj * 32 + b * 16 + lr;
      uint2 h, l;
      split4(acc[a][b][0], acc[a][b][1], acc[a][b][2], acc[a][b][3], h, l);
      const int ad = (c << 6) | (((((r0 >> 3)) ^ (c & 7)) << 3) | (r0 & 7));
      *(uint2*)(Ch + ad) = h;
      *(uint2*)(Cl + ad) = l;
    }
  }
}

// col-copy write, single fp16 plane, scaled
__device__ __forceinline__ void pack_colh(u16* C, const f32x4 acc[2][2], float sc,
                                          int wi, int wj, int g, int lr) {
#pragma unroll
  for (int a = 0; a < 2; a++) {
    const int r0 = wi * 32 + a * 16 + g * 4;
#pragma unroll
    for (int b = 0; b < 2; b++) {
      const int c = wj * 32 + b * 16 + lr;
      uint2 h;
      h.x = pkh(sc * acc[a][b][0], sc * acc[a][b][1]);
      h.y = pkh(sc * acc[a][b][2], sc * acc[a][b][3]);
      const int ad = (c << 6) | (((((r0 >> 3)) ^ (c & 7)) << 3) | (r0 & 7));
      *(uint2*)(C + ad) = h;
    }
  }
}

// dual fp16 copies for squaring: Rrow (scalar b16 scatter) + Rcol (b64)
__device__ __forceinline__ void pack_dualh(u16* Rrow, u16* Rcol, const f32x4 acc[2][2],
                                           int wi, int wj, int g, int lr) {
#pragma unroll
  for (int a = 0; a < 2; a++) {
    const int r0 = wi * 32 + a * 16 + g * 4;
#pragma unroll
    for (int b = 0; b < 2; b++) {
      const int c = wj * 32 + b * 16 + lr;
      uint2 h;
      h.x = pkh(acc[a][b][0], acc[a][b][1]);
      h.y = pkh(acc[a][b][2], acc[a][b][3]);
      const int adc = (c << 6) | (((((r0 >> 3)) ^ (c & 7)) << 3) | (r0 & 7));
      *(uint2*)(Rcol + adc) = h;
      const u16 hv[4] = {(u16)h.x, (u16)(h.x >> 16), (u16)h.y, (u16)(h.y >> 16)};
#pragma unroll
      for (int i = 0; i < 4; i++) {
        const int r = r0 + i;
        const int adr = (r << 6) | ((((c >> 3) ^ (r & 7)) << 3) | (c & 7));
        Rrow[adr] = hv[i];
      }
    }
  }
}

__global__ __launch_bounds__(256, 5)
void expm_kernel(const float* __restrict__ v, float* __restrict__ out,
                 float* __restrict__ redg) {
  __shared__ __align__(16) u16 P0[4096], P1[4096];   // A split bf16; sq dbuf set 0
  __shared__ __align__(16) u16 P2[4096], P3[4096];   // v / Af16 / X2 / X4 / S3 / sq set 1
  const int tid = threadIdx.x;
  const int bid = blockIdx.x;
  const int l = tid & 63, w = tid >> 6;
  const int g = l >> 4, lr = l & 15;
  const int wi = w >> 1, wj = w & 1;

  // 1. stage v row (2016 floats) into P2
  {
    float* vb = (float*)P2;
    const float* vr = v + (size_t)bid * KKc;
    for (int i = tid; i < KKc; i += 256) vb[i] = vr[i];
  }
  __syncthreads();   // B1

  // 2. build skew A: split-bf16 -> P0,P1; fp16 -> P3 (incremental triangle index)
  {
    const float* vb = (const float*)P2;
    const int arow = tid >> 2, q = tid & 3;
    const int ub = (arow * (127 - arow)) / 2 - arow - 1;   // upper: idx = ub + c
    const int c0 = q * 16;
    int il = (c0 * (127 - c0)) / 2 + arow - c0 - 1;        // lower idx at c0
    float va[16];
#pragma unroll
    for (int j = 0; j < 16; j++) {
      const int c = c0 + j;
      float val = 0.f;
      if (arow < c)      val =  vb[ub + c];
      else if (arow > c) val = -vb[il];
      va[j] = val;
      il += 62 - c;
    }
#pragma unroll
    for (int cc = 0; cc < 2; cc++) {
      const int ch = 2 * q + cc;
      const int ad = (arow << 6) | ((ch ^ (arow & 7)) << 3);
      unsigned hw[4], lw[4], fw[4];
#pragma unroll
      for (int p = 0; p < 4; p++) {
        const float a = va[cc * 8 + 2 * p], b = va[cc * 8 + 2 * p + 1];
        float fa, fb;
        hw[p] = pk_hi(a, b, fa, fb);
        lw[p] = pk(a - fa, b - fb);
        fw[p] = pkh(a, b);
      }
      *(u32x4*)(P0 + ad) = (u32x4){hw[0], hw[1], hw[2], hw[3]};
      *(u32x4*)(P1 + ad) = (u32x4){lw[0], lw[1], lw[2], lw[3]};
      *(u32x4*)(P3 + ad) = (u32x4){fw[0], fw[1], fw[2], fw[3]};
    }
  }
  __syncthreads();   // B2 — A planes + Af16 ready; P2 (v floats) dead

  const f32x4 zz = {0.f, 0.f, 0.f, 0.f};
  f32x4 acc[2][2];

  // 3. M = A·A^T = -A^2 (fp16); pack X2 = 2^-4 A^2 = -2^-4 M -> P2 (no plane conflict)
  acc[0][0] = zz; acc[0][1] = zz; acc[1][0] = zz; acc[1][1] = zz;
  mat_mm1h(P3, P3, acc, wi, wj, g, lr);
  f32x4 rM[2][2];
  rM[0][0] = acc[0][0]; rM[0][1] = acc[0][1]; rM[1][0] = acc[1][0]; rM[1][1] = acc[1][1];
  pack_colh(P2, rM, -0.0625f, wi, wj, g, lr);
  __syncthreads();   // B3 — X2 ready; Af16 (P3) reads done

  // 4. X4 = X2*X2 = 2^-8 A^4 (fp16); reduce ||X4||^2 -> redg; pack X4 -> P3
  acc[0][0] = zz; acc[0][1] = zz; acc[1][0] = zz; acc[1][1] = zz;
  mat_mm1h(P2, P2, acc, wi, wj, g, lr);
  {
    float fs = 0.f;
#pragma unroll
    for (int a = 0; a < 2; a++)
#pragma unroll
      for (int b = 0; b < 2; b++)
#pragma unroll
        for (int i = 0; i < 4; i++) fs = fmaf(acc[a][b][i], acc[a][b][i], fs);
#pragma unroll
    for (int k = 1; k < 64; k <<= 1) fs += __shfl_xor(fs, k, 64);
    if (l == 0) redg[bid * 4 + w] = fs;
  }
  pack_colh(P3, acc, 1.f, wi, wj, g, lr);
  __syncthreads();   // B4 — X4 ready; redg visible (barrier drains vmcnt)

  // 5. s from ||A^4||_F^{1/4} with theta=2:  s = ceil(1 + 0.125*log2(||X4||_F^2))
  const float nf8 = redg[bid * 4 + 0] + redg[bid * 4 + 1]
                  + redg[bid * 4 + 2] + redg[bid * 4 + 3];
  int s = 0;
  if (nf8 > 1e-30f) {
    s = (int)ceilf(1.0f + 0.125f * log2f(nf8));
    if (s < 0) s = 0;
    if (s > 15) s = 15;
  }
  const float t = exp2f(-(float)s);
  const float t2 = t * t, t4 = t2 * t2, t6 = t4 * t2, t8 = t4 * t4;
  const float e2 = 0.5f * t2,            e4 = 256.f * t4 / 24.f;
  const float e6 = 4096.f * t6 / 720.f,  e8 = 65536.f * t8 / 40320.f;
  const float o1 = t,                    o3 = t * t2 / 6.f;
  const float o5 = 256.f * t * t4 / 120.f, o7 = 4096.f * t * t6 / 5040.f;
  const float o9 = 65536.f * t * t8 / 362880.f;

  // fold E,S3 partials from A^2 = -M and X4acc = 2^-8 A^4
  f32x4 rE[2][2], rS3[2][2];
#pragma unroll
  for (int a = 0; a < 2; a++)
#pragma unroll
    for (int b = 0; b < 2; b++)
#pragma unroll
      for (int i = 0; i < 4; i++) {
        const int row = wi * 32 + a * 16 + g * 4 + i;
        const int col = wj * 32 + b * 16 + lr;
        const float dg = (row == col) ? 1.f : 0.f;
        rE[a][b][i]  = dg - e2 * rM[a][b][i] + e4 * acc[a][b][i];
        rS3[a][b][i] = o1 * dg - o3 * rM[a][b][i] + o5 * acc[a][b][i];
      }

  // 6. X6 = X4*X2 (=2^-12 A^6), X8 = X4*X4 (=2^-16 A^8): fp16, acc-only, fold
  acc[0][0] = zz; acc[0][1] = zz; acc[1][0] = zz; acc[1][1] = zz;
  mat_mm1h(P3, P2, acc, wi, wj, g, lr);
#pragma unroll
  for (int a = 0; a < 2; a++)
#pragma unroll
    for (int b = 0; b < 2; b++)
#pragma unroll
      for (int i = 0; i < 4; i++) {
        rE[a][b][i]  += e6 * acc[a][b][i];
        rS3[a][b][i] += o7 * acc[a][b][i];
      }
  acc[0][0] = zz; acc[0][1] = zz; acc[1][0] = zz; acc[1][1] = zz;
  mat_mm1h(P3, P3, acc, wi, wj, g, lr);
#pragma unroll
  for (int a = 0; a < 2; a++)
#pragma unroll
    for (int b = 0; b < 2; b++)
#pragma unroll
      for (int i = 0; i < 4; i++) {
        rE[a][b][i]  += e8 * acc[a][b][i];
        rS3[a][b][i] += o9 * acc[a][b][i];
      }
  __syncthreads();   // B5 — all X2/X4 reads done

  // 7. pack S3 (split bf16, symmetric): hi -> P2, lo -> P3
  pack_col(P2, P3, rS3, wi, wj, g, lr);
  __syncthreads();   // B6

  // 8. R0 = E + A*S3 (3-pass split-bf16)
  acc[0][0] = rE[0][0]; acc[0][1] = rE[0][1]; acc[1][0] = rE[1][0]; acc[1][1] = rE[1][1];
  mat_mm3(P0, P1, P2, P3, acc, wi, wj, g, lr);
  __syncthreads();   // B7 — A/S3 reads done before squaring overwrites

  // 9. s squarings, fp16, double-buffered (one barrier each)
  for (int it = 0; it < s; it++) {
    u16* Rrow = (it & 1) ? P3 : P1;
    u16* Rcol = (it & 1) ? P2 : P0;
    pack_dualh(Rrow, Rcol, acc, wi, wj, g, lr);
    __syncthreads();
    acc[0][0] = zz; acc[0][1] = zz; acc[1][0] = zz; acc[1][1] = zz;
    mat_mm1h(Rrow, Rcol, acc, wi, wj, g, lr);
  }

  // 10. store result (scalar, 64B-segment coalesced)
  float* ob = out + (size_t)bid * 4096;
#pragma unroll
  for (int a = 0; a < 2; a++)
#pragma unroll
    for (int b = 0; b < 2; b++)
#pragma unroll
      for (int i = 0; i < 4; i++) {
        const int row = wi * 32 + a * 16 + g * 4 + i;
        const int col = wj * 32 + b * 16 + lr;
        ob[row * 64 + col] = acc[a][b][i];
      }
}

extern "C" void kernel_launch(void* const* d_in, const int* in_sizes, int n_in,
                              void* d_out, int out_size, void* d_ws, size_t ws_size,
                              hipStream_t stream) {
  const float* x = (const float*)d_in[0];
  const float* W = (const float*)d_in[1];
  const float* bias = (const float*)d_in[2];
  float* out = (float*)d_out;
  char* ws = (char*)d_ws;
  float* v = (float*)ws;

  const size_t V_BYTES  = (size_t)BB * KKc * 4;    // 66,060,288
  const size_t XF_ELEMS = (size_t)BB * NF;
  const size_t WF_ELEMS = (size_t)2048 * NF;
  const size_t NEED = V_BYTES + (XF_ELEMS + WF_ELEMS) * 2;
  float* redg = (float*)(ws + V_BYTES);            // reuses xf region (dead by expm)

  if (ws_size >= NEED) {
    u16* xf = (u16*)(ws + V_BYTES);
    u16* wfp = xf + XF_ELEMS;
    prep_f16_kernel<<<dim3(BB + 2048), dim3(256), 0, stream>>>(x, W, xf, wfp);
    gemm_f16_kernel<<<dim3(1024), dim3(256), 0, stream>>>(xf, wfp, bias, v);
  } else {
    dim3 g1((KKc + BN - 1) / BN, BB / BM);
    gemm_silu_kernel<<<g1, dim3(256), 0, stream>>>(x, W, bias, v);
  }
  expm_kernel<<<dim3(BB), dim3(256), 0, stream>>>(v, out, redg);
}

// Round 13
// 166.933 us; speedup vs baseline: 1.0190x; 1.0190x over previous
//
#include <hip/hip_runtime.h>
#include <hip/hip_bf16.h>
#include <hip/hip_fp16.h>
#include <math.h>

#define BB 8192
#define NF 1024
#define KKc 2016
#define DD 64

typedef unsigned short u16;
typedef __attribute__((ext_vector_type(4))) float f32x4;
typedef __attribute__((ext_vector_type(4))) unsigned int u32x4;
typedef __attribute__((ext_vector_type(8))) short s16x8;
typedef __attribute__((ext_vector_type(8))) _Float16 f16x8;
typedef __attribute__((ext_vector_type(8))) unsigned short u16x8;

union BF2U { __hip_bfloat162 b; unsigned u; };
union H2U { __half2 h; unsigned u; };
union F16U { s16x8 s; f16x8 h; };

__device__ __forceinline__ unsigned pk_hi(float a, float b, float& fa, float& fb) {
  BF2U r; r.b = __float22bfloat162_rn(make_float2(a, b));
  float2 f = __bfloat1622float2(r.b);
  fa = f.x; fb = f.y;
  return r.u;
}
__device__ __forceinline__ unsigned pk(float a, float b) {
  BF2U r; r.b = __float22bfloat162_rn(make_float2(a, b));
  return r.u;
}
__device__ __forceinline__ unsigned pkh(float a, float b) {
  H2U r; r.h = __float22half2_rn(make_float2(a, b));
  return r.u;
}

__device__ __forceinline__ void split4(const float t0, const float t1, const float t2,
                                       const float t3, uint2& h, uint2& l) {
  float f0, f1, f2, f3;
  h.x = pk_hi(t0, t1, f0, f1);
  h.y = pk_hi(t2, t3, f2, f3);
  l.x = pk(t0 - f0, t1 - f1);
  l.y = pk(t2 - f2, t3 - f3);
}

// ---------------- Fused prepass: xf = fp16(silu(x)); wfp = fp16(W) padded ----------------
__global__ __launch_bounds__(256)
void prep_f16_kernel(const float* __restrict__ x, const float* __restrict__ W,
                     u16* __restrict__ xf, u16* __restrict__ wfp) {
  const int bid = blockIdx.x;
  if (bid < BB) {
    const int idx = bid * 256 + threadIdx.x;
    float4 vv = ((const float4*)x)[idx];
    float a[4] = {vv.x, vv.y, vv.z, vv.w};
#pragma unroll
    for (int i = 0; i < 4; i++) a[i] = a[i] / (1.f + __expf(-a[i]));
    uint2 o;
    o.x = pkh(a[0], a[1]);
    o.y = pkh(a[2], a[3]);
    ((uint2*)xf)[idx] = o;
  } else {
    const int idx = (bid - BB) * 256 + threadIdx.x;
    const int row = idx >> 8;
    float4 vv = make_float4(0.f, 0.f, 0.f, 0.f);
    if (row < KKc) vv = ((const float4*)W)[idx];
    uint2 o;
    o.x = pkh(vv.x, vv.y);
    o.y = pkh(vv.z, vv.w);
    ((uint2*)wfp)[idx] = o;
  }
}

// ---------------- Kernel 1: v = silu(x)@W^T + b via 1-pass fp16 MFMA ----------------
typedef __attribute__((address_space(1))) const unsigned int gu32;
typedef __attribute__((address_space(3))) unsigned int lu32;

__device__ __forceinline__ void gload_lds16(const void* g, void* l) {
  __builtin_amdgcn_global_load_lds((gu32*)g, (lu32*)l, 16, 0, 0);
}

__device__ __forceinline__ s16x8 frag_row32(const u16* T, int row, int kc) {
  const int c = kc ^ ((row >> 1) & 3);
  return *(const s16x8*)(T + row * 32 + c * 8);
}

__global__ __launch_bounds__(256, 4)
void gemm_f16_kernel(const u16* __restrict__ xf, const u16* __restrict__ wfp,
                     const float* __restrict__ bias, float* __restrict__ v) {
  __shared__ __align__(16) u16 Af[128 * 32];
  __shared__ __align__(16) u16 Bf[128 * 32];
  const int tid = threadIdx.x;
  const int l = tid & 63, w = tid >> 6;
  const int wi = w >> 1, wj = w & 1;
  const int lin = (blockIdx.x & 7) * 128 + (blockIdx.x >> 3);
  const int n0 = (lin & 15) * 128;
  const int m0 = (lin >> 4) * 128;
  const int kc = l >> 4, lr = l & 15;

  const u16* P = (w < 2) ? xf : wfp;
  u16* T = (w < 2) ? Af : Bf;
  const int row0 = ((w < 2) ? m0 : n0) + (w & 1) * 64;
  u16* Th = T + (w & 1) * 2048;

  f32x4 acc[4][4];
  const f32x4 zz = {0.f, 0.f, 0.f, 0.f};
#pragma unroll
  for (int a = 0; a < 4; a++)
#pragma unroll
    for (int b = 0; b < 4; b++) acc[a][b] = zz;

  for (int k0 = 0; k0 < NF; k0 += 32) {
#pragma unroll
    for (int c4 = 0; c4 < 4; c4++) {
      const int slot = c4 * 64 + l;
      const int r = slot >> 2;
      const int c = (slot & 3) ^ ((r >> 1) & 3);
      gload_lds16(P + (size_t)(row0 + r) * NF + k0 + c * 8, Th + c4 * 512);
    }
    __syncthreads();

    F16U fa[4], fb[4];
#pragma unroll
    for (int a = 0; a < 4; a++) fa[a].s = frag_row32(Af, wi * 64 + a * 16 + lr, kc);
#pragma unroll
    for (int b = 0; b < 4; b++) fb[b].s = frag_row32(Bf, wj * 64 + b * 16 + lr, kc);
#pragma unroll
    for (int b = 0; b < 4; b++)
#pragma unroll
      for (int a = 0; a < 4; a++)
        acc[a][b] = __builtin_amdgcn_mfma_f32_16x16x32_f16(fa[a].h, fb[b].h, acc[a][b], 0, 0, 0);
    __syncthreads();
  }

  const int grp = l >> 4;
#pragma unroll
  for (int b = 0; b < 4; b++) {
    const int n = n0 + wj * 64 + b * 16 + lr;
    if (n < KKc) {
      const float bb = bias[n];
#pragma unroll
      for (int a = 0; a < 4; a++) {
        const int mbase = m0 + wi * 64 + a * 16 + grp * 4;
#pragma unroll
        for (int i = 0; i < 4; i++)
          v[(size_t)(mbase + i) * KKc + n] = acc[a][b][i] + bb;
      }
    }
  }
}

// ---------------- Fallback fp32 GEMM (if ws too small) ----------------
#define BM 128
#define BN 128
#define BKr 16
#define XST 132

__global__ __launch_bounds__(256, 2)
void gemm_silu_kernel(const float* __restrict__ x, const float* __restrict__ W,
                      const float* __restrict__ bias, float* __restrict__ v) {
  __shared__ float xs[BKr * XST];
  __shared__ float wl[BKr * XST];
  const int tid = threadIdx.x;
  const int tx = tid & 15, ty = tid >> 4;
  const int c0g = blockIdx.x * BN;
  const int m0 = blockIdx.y * BM;
  const int lrow = tid >> 2;
  const int lu = (tid & 3) << 2;

  float acc[2][2][4][4];
#pragma unroll
  for (int a = 0; a < 2; a++)
#pragma unroll
    for (int b = 0; b < 2; b++)
#pragma unroll
      for (int i = 0; i < 4; i++)
#pragma unroll
        for (int j = 0; j < 4; j++) acc[a][b][i][j] = 0.f;

  for (int n0 = 0; n0 < NF; n0 += BKr) {
#pragma unroll
    for (int p = 0; p < 2; p++) {
      const int row = lrow + 64 * p;
      float4 xv = *(const float4*)(x + (size_t)(m0 + row) * NF + n0 + lu);
      float xa[4] = {xv.x, xv.y, xv.z, xv.w};
#pragma unroll
      for (int u = 0; u < 4; u++) {
        const float val = xa[u];
        xs[(lu + u) * XST + row] = val / (1.f + __expf(-val));
      }
      const int wr = c0g + row;
      float4 wv = make_float4(0.f, 0.f, 0.f, 0.f);
      if (wr < KKc) wv = *(const float4*)(W + (size_t)wr * NF + n0 + lu);
      float wa[4] = {wv.x, wv.y, wv.z, wv.w};
#pragma unroll
      for (int u = 0; u < 4; u++) wl[(lu + u) * XST + row] = wa[u];
    }
    __syncthreads();
#pragma unroll
    for (int k0 = 0; k0 < BKr; k0 += 4) {
#pragma unroll
      for (int kk = 0; kk < 4; kk++) {
        const float* xr = xs + (k0 + kk) * XST;
        const float* wr_ = wl + (k0 + kk) * XST;
        float4 t;
        t = *(const float4*)(xr + 4 * ty);       float a0[4] = {t.x, t.y, t.z, t.w};
        t = *(const float4*)(xr + 64 + 4 * ty);  float a1[4] = {t.x, t.y, t.z, t.w};
        t = *(const float4*)(wr_ + 4 * tx);      float b0[4] = {t.x, t.y, t.z, t.w};
        t = *(const float4*)(wr_ + 64 + 4 * tx); float b1[4] = {t.x, t.y, t.z, t.w};
#pragma unroll
        for (int i = 0; i < 4; i++)
#pragma unroll
          for (int j = 0; j < 4; j++) {
            acc[0][0][i][j] = fmaf(a0[i], b0[j], acc[0][0][i][j]);
            acc[0][1][i][j] = fmaf(a0[i], b1[j], acc[0][1][i][j]);
            acc[1][0][i][j] = fmaf(a1[i], b0[j], acc[1][0][i][j]);
            acc[1][1][i][j] = fmaf(a1[i], b1[j], acc[1][1][i][j]);
          }
      }
    }
    __syncthreads();
  }
#pragma unroll
  for (int rb = 0; rb < 2; rb++)
#pragma unroll
    for (int ii = 0; ii < 4; ii++) {
      const int row = m0 + rb * 64 + 4 * ty + ii;
#pragma unroll
      for (int cb = 0; cb < 2; cb++) {
        const int c = c0g + cb * 64 + 4 * tx;
        if (c < KKc) {
          float4 bb = *(const float4*)(bias + c);
          float4 o;
          o.x = acc[rb][cb][ii][0] + bb.x;
          o.y = acc[rb][cb][ii][1] + bb.y;
          o.z = acc[rb][cb][ii][2] + bb.z;
          o.w = acc[rb][cb][ii][3] + bb.w;
          *(float4*)(v + (size_t)row * KKc + c) = o;
        }
      }
    }
}

// ---------------- Kernel 2: expm(skew(v_row)) ----------------
// Plane layout: u16[64][64]; 16B chunk swizzle chunk' = chunk ^ (row&7).
// mat_mm1h(P,Q) computes rows(P)·rows(Q)^T. Skew A: A·A^T = -A^2.
// Fixed exact prescales (powers of 2): X2 = 2^-4 A^2 (fp16), X4 = 2^-8 A^4.

__device__ __forceinline__ s16x8 fragld(const u16* P, int row, int chunk) {
  return *(const s16x8*)(P + ((row << 6) | ((chunk ^ (row & 7)) << 3)));
}

// split-bf16 3-pass: acc += A·B (B symmetric, row-read)
__device__ __forceinline__ void mat_mm3(const u16* APh, const u16* APl,
                                        const u16* BPh, const u16* BPl,
                                        f32x4 acc[2][2], int wi, int wj, int g, int lr) {
#pragma unroll
  for (int kb = 0; kb < 2; kb++) {
    const int ch = (kb << 2) | g;
    s16x8 bh[2], bl[2];
#pragma unroll
    for (int b = 0; b < 2; b++) {
      const int n = wj * 32 + b * 16 + lr;
      bh[b] = fragld(BPh, n, ch);
      bl[b] = fragld(BPl, n, ch);
    }
#pragma unroll
    for (int a = 0; a < 2; a++) {
      const int r = wi * 32 + a * 16 + lr;
      const s16x8 ah = fragld(APh, r, ch);
      const s16x8 al = fragld(APl, r, ch);
#pragma unroll
      for (int b = 0; b < 2; b++) {
        acc[a][b] = __builtin_amdgcn_mfma_f32_16x16x32_bf16(ah, bh[b], acc[a][b], 0, 0, 0);
        acc[a][b] = __builtin_amdgcn_mfma_f32_16x16x32_bf16(ah, bl[b], acc[a][b], 0, 0, 0);
        acc[a][b] = __builtin_amdgcn_mfma_f32_16x16x32_bf16(al, bh[b], acc[a][b], 0, 0, 0);
      }
    }
  }
}

// fp16 1-pass: acc += rows(AP)·rows(BP)^T
__device__ __forceinline__ void mat_mm1h(const u16* AP, const u16* BP,
                                         f32x4 acc[2][2], int wi, int wj, int g, int lr) {
#pragma unroll
  for (int kb = 0; kb < 2; kb++) {
    const int ch = (kb << 2) | g;
    F16U bh[2];
#pragma unroll
    for (int b = 0; b < 2; b++) bh[b].s = fragld(BP, wj * 32 + b * 16 + lr, ch);
#pragma unroll
    for (int a = 0; a < 2; a++) {
      F16U ah; ah.s = fragld(AP, wi * 32 + a * 16 + lr, ch);
#pragma unroll
      for (int b = 0; b < 2; b++)
        acc[a][b] = __builtin_amdgcn_mfma_f32_16x16x32_f16(ah.h, bh[b].h, acc[a][b], 0, 0, 0);
    }
  }
}

// col-copy write, split bf16 (symmetric => col-copy == row-major)
__device__ __forceinline__ void pack_col(u16* Ch, u16* Cl, const f32x4 acc[2][2],
                                         int wi, int wj, int g, int lr) {
#pragma unroll
  for (int a = 0; a < 2; a++) {
    const int r0 = wi * 32 + a * 16 + g * 4;
#pragma unroll
    for (int b = 0; b < 2; b++) {
      const int c = wj * 32 + b * 16 + lr;
      uint2 h, l;
      split4(acc[a][b][0], acc[a][b][1], acc[a][b][2], acc[a][b][3], h, l);
      const int ad = (c << 6) | (((((r0 >> 3)) ^ (c & 7)) << 3) | (r0 & 7));
      *(uint2*)(Ch + ad) = h;
      *(uint2*)(Cl + ad) = l;
    }
  }
}

// col-copy write, single fp16 plane, scaled
__device__ __forceinline__ void pack_colh(u16* C, const f32x4 acc[2][2], float sc,
                                          int wi, int wj, int g, int lr) {
#pragma unroll
  for (int a = 0; a < 2; a++) {
    const int r0 = wi * 32 + a * 16 + g * 4;
#pragma unroll
    for (int b = 0; b < 2; b++) {
      const int c = wj * 32 + b * 16 + lr;
      uint2 h;
      h.x = pkh(sc * acc[a][b][0], sc * acc[a][b][1]);
      h.y = pkh(sc * acc[a][b][2], sc * acc[a][b][3]);
      const int ad = (c << 6) | (((((r0 >> 3)) ^ (c & 7)) << 3) | (r0 & 7));
      *(uint2*)(C + ad) = h;
    }
  }
}

// dual fp16 copies for squaring: Rrow (scalar b16 scatter) + Rcol (b64)
__device__ __forceinline__ void pack_dualh(u16* Rrow, u16* Rcol, const f32x4 acc[2][2],
                                           int wi, int wj, int g, int lr) {
#pragma unroll
  for (int a = 0; a < 2; a++) {
    const int r0 = wi * 32 + a * 16 + g * 4;
#pragma unroll
    for (int b = 0; b < 2; b++) {
      const int c = wj * 32 + b * 16 + lr;
      uint2 h;
      h.x = pkh(acc[a][b][0], acc[a][b][1]);
      h.y = pkh(acc[a][b][2], acc[a][b][3]);
      const int adc = (c << 6) | (((((r0 >> 3)) ^ (c & 7)) << 3) | (r0 & 7));
      *(uint2*)(Rcol + adc) = h;
      const u16 hv[4] = {(u16)h.x, (u16)(h.x >> 16), (u16)h.y, (u16)(h.y >> 16)};
#pragma unroll
      for (int i = 0; i < 4; i++) {
        const int r = r0 + i;
        const int adr = (r << 6) | ((((c >> 3) ^ (r & 7)) << 3) | (c & 7));
        Rrow[adr] = hv[i];
      }
    }
  }
}

__global__ __launch_bounds__(256, 4)
void expm_kernel(const float* __restrict__ v, float* __restrict__ out) {
  __shared__ __align__(16) u16 P0[4096], P1[4096];   // A split bf16; sq dbuf set 0
  __shared__ __align__(16) u16 P2[4096], P3[4096];   // Af16 / X2 / X4 / S3 / sq set 1
  __shared__ float red[4];
  const int tid = threadIdx.x;
  const int bid = blockIdx.x;
  const int l = tid & 63, w = tid >> 6;
  const int g = l >> 4, lr = l & 15;
  const int wi = w >> 1, wj = w & 1;

  // 1. build skew A directly from global v (8KB window, L2-absorbed; no LDS stage)
  {
    const float* vr = v + (size_t)bid * KKc;
    const int arow = tid >> 2, q = tid & 3;
    const int ub = (arow * (127 - arow)) / 2 - arow - 1;   // upper: idx = ub + c
    const int c0 = q * 16;
    int il = (c0 * (127 - c0)) / 2 + arow - c0 - 1;        // lower idx at c0
    float va[16];
#pragma unroll
    for (int j = 0; j < 16; j++) {
      const int c = c0 + j;
      float val = 0.f;
      if (arow < c)      val =  vr[ub + c];
      else if (arow > c) val = -vr[il];
      va[j] = val;
      il += 62 - c;
    }
#pragma unroll
    for (int cc = 0; cc < 2; cc++) {
      const int ch = 2 * q + cc;
      const int ad = (arow << 6) | ((ch ^ (arow & 7)) << 3);
      unsigned hw[4], lw[4], fw[4];
#pragma unroll
      for (int p = 0; p < 4; p++) {
        const float a = va[cc * 8 + 2 * p], b = va[cc * 8 + 2 * p + 1];
        float fa, fb;
        hw[p] = pk_hi(a, b, fa, fb);
        lw[p] = pk(a - fa, b - fb);
        fw[p] = pkh(a, b);
      }
      *(u32x4*)(P0 + ad) = (u32x4){hw[0], hw[1], hw[2], hw[3]};
      *(u32x4*)(P1 + ad) = (u32x4){lw[0], lw[1], lw[2], lw[3]};
      *(u32x4*)(P3 + ad) = (u32x4){fw[0], fw[1], fw[2], fw[3]};
    }
  }
  __syncthreads();   // B1 — A planes + Af16 ready

  const f32x4 zz = {0.f, 0.f, 0.f, 0.f};
  f32x4 acc[2][2];

  // 2. M = A·A^T = -A^2 (fp16); pack X2 = -2^-4 M -> P2
  acc[0][0] = zz; acc[0][1] = zz; acc[1][0] = zz; acc[1][1] = zz;
  mat_mm1h(P3, P3, acc, wi, wj, g, lr);
  f32x4 rM[2][2];
  rM[0][0] = acc[0][0]; rM[0][1] = acc[0][1]; rM[1][0] = acc[1][0]; rM[1][1] = acc[1][1];
  pack_colh(P2, rM, -0.0625f, wi, wj, g, lr);
  __syncthreads();   // B2 — X2 ready; Af16 (P3) reads done

  // 3. X4 = X2*X2 = 2^-8 A^4 (fp16); reduce ||X4||^2 -> red (LDS); pack X4 -> P3
  acc[0][0] = zz; acc[0][1] = zz; acc[1][0] = zz; acc[1][1] = zz;
  mat_mm1h(P2, P2, acc, wi, wj, g, lr);
  {
    float fs = 0.f;
#pragma unroll
    for (int a = 0; a < 2; a++)
#pragma unroll
      for (int b = 0; b < 2; b++)
#pragma unroll
        for (int i = 0; i < 4; i++) fs = fmaf(acc[a][b][i], acc[a][b][i], fs);
#pragma unroll
    for (int k = 1; k < 64; k <<= 1) fs += __shfl_xor(fs, k, 64);
    if (l == 0) red[w] = fs;
  }
  pack_colh(P3, acc, 1.f, wi, wj, g, lr);
  __syncthreads();   // B3 — X4 + red ready

  // 4. s from ||A^4||_F^{1/4} with theta=2:  s = ceil(1 + 0.125*log2(||X4||_F^2))
  const float nf8 = red[0] + red[1] + red[2] + red[3];
  int s = 0;
  if (nf8 > 1e-30f) {
    s = (int)ceilf(1.0f + 0.125f * log2f(nf8));
    if (s < 0) s = 0;
    if (s > 15) s = 15;
  }
  const float t = exp2f(-(float)s);
  const float t2 = t * t, t4 = t2 * t2, t6 = t4 * t2, t8 = t4 * t4;
  const float e2 = 0.5f * t2,            e4 = 256.f * t4 / 24.f;
  const float e6 = 4096.f * t6 / 720.f,  e8 = 65536.f * t8 / 40320.f;
  const float o1 = t,                    o3 = t * t2 / 6.f;
  const float o5 = 256.f * t * t4 / 120.f, o7 = 4096.f * t * t6 / 5040.f;
  const float o9 = 65536.f * t * t8 / 362880.f;

  // fold E,S3 partials from A^2 = -M and X4acc = 2^-8 A^4
  f32x4 rE[2][2], rS3[2][2];
#pragma unroll
  for (int a = 0; a < 2; a++)
#pragma unroll
    for (int b = 0; b < 2; b++)
#pragma unroll
      for (int i = 0; i < 4; i++) {
        const int row = wi * 32 + a * 16 + g * 4 + i;
        const int col = wj * 32 + b * 16 + lr;
        const float dg = (row == col) ? 1.f : 0.f;
        rE[a][b][i]  = dg - e2 * rM[a][b][i] + e4 * acc[a][b][i];
        rS3[a][b][i] = o1 * dg - o3 * rM[a][b][i] + o5 * acc[a][b][i];
      }

  // 5. X6 = X4*X2 (=2^-12 A^6), X8 = X4*X4 (=2^-16 A^8): fp16, acc-only, fold
  acc[0][0] = zz; acc[0][1] = zz; acc[1][0] = zz; acc[1][1] = zz;
  mat_mm1h(P3, P2, acc, wi, wj, g, lr);
#pragma unroll
  for (int a = 0; a < 2; a++)
#pragma unroll
    for (int b = 0; b < 2; b++)
#pragma unroll
      for (int i = 0; i < 4; i++) {
        rE[a][b][i]  += e6 * acc[a][b][i];
        rS3[a][b][i] += o7 * acc[a][b][i];
      }
  acc[0][0] = zz; acc[0][1] = zz; acc[1][0] = zz; acc[1][1] = zz;
  mat_mm1h(P3, P3, acc, wi, wj, g, lr);
#pragma unroll
  for (int a = 0; a < 2; a++)
#pragma unroll
    for (int b = 0; b < 2; b++)
#pragma unroll
      for (int i = 0; i < 4; i++) {
        rE[a][b][i]  += e8 * acc[a][b][i];
        rS3[a][b][i] += o9 * acc[a][b][i];
      }
  __syncthreads();   // B4 — all X2/X4 reads done

  // 6. pack S3 (split bf16, symmetric): hi -> P2, lo -> P3
  pack_col(P2, P3, rS3, wi, wj, g, lr);
  __syncthreads();   // B5

  // 7. R0 = E + A*S3 (3-pass split-bf16)
  acc[0][0] = rE[0][0]; acc[0][1] = rE[0][1]; acc[1][0] = rE[1][0]; acc[1][1] = rE[1][1];
  mat_mm3(P0, P1, P2, P3, acc, wi, wj, g, lr);
  __syncthreads();   // B6 — A/S3 reads done before squaring overwrites

  // 8. s squarings, fp16, double-buffered (one barrier each)
  for (int it = 0; it < s; it++) {
    u16* Rrow = (it & 1) ? P3 : P1;
    u16* Rcol = (it & 1) ? P2 : P0;
    pack_dualh(Rrow, Rcol, acc, wi, wj, g, lr);
    __syncthreads();
    acc[0][0] = zz; acc[0][1] = zz; acc[1][0] = zz; acc[1][1] = zz;
    mat_mm1h(Rrow, Rcol, acc, wi, wj, g, lr);
  }

  // 9. store result (scalar, 64B-segment coalesced)
  float* ob = out + (size_t)bid * 4096;
#pragma unroll
  for (int a = 0; a < 2; a++)
#pragma unroll
    for (int b = 0; b < 2; b++)
#pragma unroll
      for (int i = 0; i < 4; i++) {
        const int row = wi * 32 + a * 16 + g * 4 + i;
        const int col = wj * 32 + b * 16 + lr;
        ob[row * 64 + col] = acc[a][b][i];
      }
}

extern "C" void kernel_launch(void* const* d_in, const int* in_sizes, int n_in,
                              void* d_out, int out_size, void* d_ws, size_t ws_size,
                              hipStream_t stream) {
  const float* x = (const float*)d_in[0];
  const float* W = (const float*)d_in[1];
  const float* bias = (const float*)d_in[2];
  float* out = (float*)d_out;
  char* ws = (char*)d_ws;
  float* v = (float*)ws;

  const size_t V_BYTES  = (size_t)BB * KKc * 4;    // 66,060,288
  const size_t XF_ELEMS = (size_t)BB * NF;
  const size_t WF_ELEMS = (size_t)2048 * NF;
  const size_t NEED = V_BYTES + (XF_ELEMS + WF_ELEMS) * 2;

  if (ws_size >= NEED) {
    u16* xf = (u16*)(ws + V_BYTES);
    u16* wfp = xf + XF_ELEMS;
    prep_f16_kernel<<<dim3(BB + 2048), dim3(256), 0, stream>>>(x, W, xf, wfp);
    gemm_f16_kernel<<<dim3(1024), dim3(256), 0, stream>>>(xf, wfp, bias, v);
  } else {
    dim3 g1((KKc + BN - 1) / BN, BB / BM);
    gemm_silu_kernel<<<g1, dim3(256), 0, stream>>>(x, W, bias, v);
  }
  expm_kernel<<<dim3(BB), dim3(256), 0, stream>>>(v, out);
}